// Round 11
// baseline (339.207 us; speedup 1.0000x reference)
//
#include <hip/hip_runtime.h>
#include <math.h>

#define NTP 256     // prep kernel block
#define NT 64       // main kernel: ONE wave per block, TWO batch elements interleaved
#define NS 4096     // 2^12 amplitudes

typedef float f32x2 __attribute__((ext_vector_type(2)));

// CNOT ring: gates CNOT(i,(i+1)%12), wire j <-> bit (11-j).
// forward basis permutation pi(k), GF(2)-linear:
constexpr int ring_pi_c(int k) {
    int u = k ^ (k >> 1);
    u ^= u >> 2; u ^= u >> 4; u ^= u >> 8;
    int w0 = ((u >> 11) ^ u) & 1;
    return (u & 0x7FF) | (w0 << 11);
}
// storage swizzle: low nibble ^= g(k[9:6]); verified conflict-free for A-pass,
// B-pass and ring-scatter (R8: SQ_LDS_BANK_CONFLICT == 0 on hardware).
constexpr int gfun(int n) {
    int n0 = n & 1, n1 = (n >> 1) & 1, n2 = (n >> 2) & 1, n3 = (n >> 3) & 1;
    return (n1) | ((n0 ^ n1 ^ n2) << 1) | ((n0 ^ n2 ^ n3) << 2) | ((n0 ^ n3) << 3);
}
constexpr int sigf(int k) { return k ^ gfun((k >> 6) & 15); }

// Fused gate G = [[A-iB, -C+iD],[C+iD, A+iB]] applied to (a0,a1), packed fp32.
__device__ __forceinline__ void app1p(f32x2 ab, f32x2 cd, f32x2& a0, f32x2& a1) {
    f32x2 n0, n1;
    asm("v_pk_mul_f32 %0, %2, %4 op_sel:[0,0] op_sel_hi:[1,0]\n\t"
        "v_pk_fma_f32 %0, %2, %4, %0 op_sel:[1,1,0] op_sel_hi:[0,1,1] neg_hi:[0,1,0]\n\t"
        "v_pk_fma_f32 %0, %3, %5, %0 op_sel:[0,0,0] op_sel_hi:[1,0,1] neg_lo:[0,1,0] neg_hi:[0,1,0]\n\t"
        "v_pk_fma_f32 %0, %3, %5, %0 op_sel:[1,1,0] op_sel_hi:[0,1,1] neg_lo:[0,1,0]\n\t"
        "v_pk_mul_f32 %1, %3, %4 op_sel:[0,0] op_sel_hi:[1,0]\n\t"
        "v_pk_fma_f32 %1, %3, %4, %1 op_sel:[1,1,0] op_sel_hi:[0,1,1] neg_lo:[0,1,0]\n\t"
        "v_pk_fma_f32 %1, %2, %5, %1 op_sel:[0,0,0] op_sel_hi:[1,0,1]\n\t"
        "v_pk_fma_f32 %1, %2, %5, %1 op_sel:[1,1,0] op_sel_hi:[0,1,1] neg_lo:[0,1,0]"
        : "=&v"(n0), "=&v"(n1)
        : "v"(a0), "v"(a1), "v"(ab), "v"(cd));
    a0 = n0; a1 = n1;
}

template<int P>
__device__ __forceinline__ void gate_on_bit6(f32x2 a[64], f32x2 ab, f32x2 cd) {
    #pragma unroll
    for (int r = 0; r < 64; ++r)
        if (!(r & (1 << P)))
            app1p(ab, cd, a[r], a[r | (1 << P)]);
}

// load fused gate gi (wire w); if fold, right-multiply by RX from cs12[w]
__device__ __forceinline__ void load_gate(const float4* __restrict__ Uw,
                                          const float2* __restrict__ cs12,
                                          int gi, int w, bool fold,
                                          f32x2& ab, f32x2& cd) {
    float4 g = Uw[gi];
    float A = g.x, B = g.y, C = g.z, D = g.w;
    if (fold) {
        float2 sc = cs12[w];
        float c = sc.x, s = sc.y;
        float A2 = A*c + D*s, B2 = B*c - C*s, C2 = C*c + B*s, D2 = D*c - A*s;
        A = A2; B = B2; C = C2; D = D2;
    }
    ab = f32x2{A, B}; cd = f32x2{C, D};
}

// 6 gates of one half-layer, all register-local
__device__ __forceinline__ void gates6(f32x2 a[64], const float4* __restrict__ Uw,
                                       const float2* __restrict__ cs12,
                                       int lay, int half, bool fold) {
    const int base = lay * 12 + half * 6, wb = half * 6;
    f32x2 gab, gcd;
    load_gate(Uw, cs12, base + 0, wb + 0, fold, gab, gcd); gate_on_bit6<5>(a, gab, gcd);
    load_gate(Uw, cs12, base + 1, wb + 1, fold, gab, gcd); gate_on_bit6<4>(a, gab, gcd);
    load_gate(Uw, cs12, base + 2, wb + 2, fold, gab, gcd); gate_on_bit6<3>(a, gab, gcd);
    load_gate(Uw, cs12, base + 3, wb + 3, fold, gab, gcd); gate_on_bit6<2>(a, gab, gcd);
    load_gate(Uw, cs12, base + 4, wb + 4, fold, gab, gcd); gate_on_bit6<1>(a, gab, gcd);
    load_gate(Uw, cs12, base + 5, wb + 5, fold, gab, gcd); gate_on_bit6<0>(a, gab, gcd);
}

// transpose write / read; ring=false: A->B plain, ring=true: B->A with CNOT-ring fold
__device__ __forceinline__ void Twr(f32x2* psi, const f32x2 a[64], int ln, int baseR, bool ring) {
    if (!ring) {
        #pragma unroll
        for (int r = 0; r < 64; ++r) psi[(r << 6) | (ln ^ gfun(r & 15))] = a[r];
    } else {
        #pragma unroll
        for (int r = 0; r < 64; ++r) psi[baseR ^ sigf(ring_pi_c(r))] = a[r];
    }
}
__device__ __forceinline__ void Trd(const f32x2* psi, f32x2 a[64], int ln, int baseB, bool ring) {
    if (!ring) {
        #pragma unroll
        for (int r = 0; r < 64; ++r) a[r] = psi[(baseB ^ (r & 15)) | (r & 48)];
    } else {
        #pragma unroll
        for (int r = 0; r < 64; ++r) a[r] = psi[(r << 6) | (ln ^ gfun(r & 15))];
    }
}

// init: |0..0> + first RX layer = product state, in state-A registers
__device__ __forceinline__ void init_state(f32x2 a[64], const float2* __restrict__ csb, int ln) {
    float2 rc[12];
    #pragma unroll
    for (int i = 0; i < 12; ++i) rc[i] = csb[i];
    float mlan = 1.f;
    #pragma unroll
    for (int bit = 0; bit < 6; ++bit)          // lane bit t <-> k bit t <-> wire 11-t
        mlan *= ((ln >> bit) & 1) ? rc[11 - bit].y : rc[11 - bit].x;
    int q = __popc(ln) & 3;
    float pre = (q == 0) ? mlan : (q == 2) ? -mlan : 0.f;
    float pim = (q == 1) ? -mlan : (q == 3) ? mlan : 0.f;
    float mA[8], mB[8];
    #pragma unroll
    for (int i = 0; i < 8; ++i) {
        mA[i] = (((i>>2)&1)?rc[0].y:rc[0].x) * (((i>>1)&1)?rc[1].y:rc[1].x) * ((i&1)?rc[2].y:rc[2].x);
        mB[i] = (((i>>2)&1)?rc[3].y:rc[3].x) * (((i>>1)&1)?rc[4].y:rc[4].x) * ((i&1)?rc[5].y:rc[5].x);
    }
    #pragma unroll
    for (int r = 0; r < 64; ++r) {
        float m = mA[r >> 3] * mB[r & 7];
        const int rot = __popc(r) & 3;
        float vx, vy;
        if (rot == 0)      { vx =  pre * m; vy =  pim * m; }
        else if (rot == 1) { vx =  pim * m; vy = -pre * m; }
        else if (rot == 2) { vx = -pre * m; vy = -pim * m; }
        else               { vx = -pim * m; vy =  pre * m; }
        a[r] = f32x2{vx, vy};
    }
}

// ---- prep kernel: cos/sin of all encode half-angles + batch-independent fused U
__global__ void prep_kernel(const float* __restrict__ x,     // (B,24)
                            const float* __restrict__ wts,   // (6,3,12)
                            float4* __restrict__ Uw,         // 72
                            float2* __restrict__ cs,         // B*24
                            int total)                       // B*24
{
    int idx = blockIdx.x * blockDim.x + threadIdx.x;
    if (idx < total) {
        float th = 0.5f * x[idx];
        float s, c; sincosf(th, &s, &c);
        cs[idx] = make_float2(c, s);
    }
    if (idx < 72) {
        int ab = idx / 12, w = idx % 12;
        float a  = 0.5f * wts[(ab * 3 + 0) * 12 + w];
        float bb = 0.5f * wts[(ab * 3 + 1) * 12 + w];
        float g  = 0.5f * wts[(ab * 3 + 2) * 12 + w];
        float sa, ca, sb, cb, sg, cg;
        sincosf(a,  &sa, &ca);
        sincosf(bb, &sb, &cb);
        sincosf(g,  &sg, &cg);
        float A = cb * (ca * cg - sa * sg);
        float B = sb * (ca * cg + sa * sg);
        float C = cb * (sa * cg + ca * sg);
        float D = sb * (sa * cg - ca * sg);
        Uw[idx] = make_float4(A, B, C, D);
    }
}

// One wave, TWO batch elements (aa, ab) interleaved; one shared 32KB psi buffer,
// time-multiplexed w0->r0->w1->r1 per half-layer. Each element's DS latency is
// covered by the other element's 1536-inst gate block. No cross-wave barriers.
__global__ __launch_bounds__(NT, 1)
void tqhea_kernel(const float4* __restrict__ Uw,   // 72 fused gates (ABCD)
                  const float2* __restrict__ cs,   // (B,24) encode (cos,sin)
                  float* __restrict__ out)         // (B,1)
{
    __shared__ f32x2 psi[NS];        // 32 KB, sigf-swizzled, shared by both elements

    const int ln  = threadIdx.x;                   // lane 0..63
    const int b0  = blockIdx.x << 1;
    const int b1  = b0 | 1;

    const float2* cs0  = cs + b0 * 24;
    const float2* cs1  = cs + b1 * 24;
    const float2* cs12_0 = cs0 + 12;
    const float2* cs12_1 = cs1 + 12;

    f32x2 aa[64], ab[64];
    init_state(aa, cs0, ln);
    init_state(ab, cs1, ln);

    const int gl    = gfun(ln & 15);
    const int baseB = (ln << 6) | gl;              // B-read: idx = (baseB ^ (r&15)) | (r&48)
    const int baseR = sigf(ring_pi_c(ln << 6));    // ring scatter: idx = baseR ^ sigf(pi(r))

    // ---- 11 half-phases: p even = A-half (wires 0-5) + plain transpose,
    //      p odd = B-half (wires 6-11) + ring transpose. p=11 peeled (no transpose).
    #pragma unroll 1
    for (int p = 0; p < 11; ++p) {
        const int lay = p >> 1, half = p & 1;
        const bool fold = (lay == 3);
        const bool ring = (half == 1);

        gates6(aa, Uw, cs12_0, lay, half, fold);   // covers ab's trailing reads (prev iter)
        __syncthreads();                           // el1 reads drained before overwrite
        Twr(psi, aa, ln, baseR, ring);
        gates6(ab, Uw, cs12_1, lay, half, fold);   // covers aa's writes
        __syncthreads();                           // aa writes complete
        Trd(psi, aa, ln, baseB, ring);
        __syncthreads();                           // aa reads complete before overwrite
        Twr(psi, ab, ln, baseR, ring);
        __syncthreads();                           // ab writes complete
        Trd(psi, ab, ln, baseB, ring);             // trailing; covered by next gates6(aa)
    }

    // ---- p=11: final B-half; ring + <H> fold into the reduction
    gates6(aa, Uw, cs12_0, 5, 1, false);
    gates6(ab, Uw, cs12_1, 5, 1, false);

    const int Pl = ring_pi_c(ln << 6);
    float acc0 = 0.f, acc1 = 0.f;
    #pragma unroll
    for (int r = 0; r < 64; ++r) {
        float d = 12.0f - 2.0f * (float)__popc(Pl ^ ring_pi_c(r));
        acc0 += (aa[r].x * aa[r].x + aa[r].y * aa[r].y) * d;
        acc1 += (ab[r].x * ab[r].x + ab[r].y * ab[r].y) * d;
    }
    #pragma unroll
    for (int off = 32; off > 0; off >>= 1) {
        acc0 += __shfl_down(acc0, off);
        acc1 += __shfl_down(acc1, off);
    }
    if (ln == 0) { out[b0] = acc0; out[b1] = acc1; }
}

extern "C" void kernel_launch(void* const* d_in, const int* in_sizes, int n_in,
                              void* d_out, int out_size, void* d_ws, size_t ws_size,
                              hipStream_t stream) {
    const float* x   = (const float*)d_in[0];   // (B, 24) float32
    const float* wts = (const float*)d_in[1];   // (6, 3, 12) float32
    float* out = (float*)d_out;                 // (B, 1) float32
    int B = in_sizes[0] / 24;

    float4* Uw = (float4*)d_ws;                       // 72 * 16 B
    float2* cs = (float2*)((char*)d_ws + 1152);       // B*24 * 8 B
    int total = B * 24;

    prep_kernel<<<dim3((total + NTP - 1) / NTP), dim3(NTP), 0, stream>>>(x, wts, Uw, cs, total);
    tqhea_kernel<<<dim3(B / 2), dim3(NT), 0, stream>>>(Uw, cs, out);
}

// Round 12
// 202.167 us; speedup vs baseline: 1.6779x; 1.6779x over previous
//
#include <hip/hip_runtime.h>
#include <math.h>

#define NTP 256
#define NT 256      // main kernel threads
#define NS 4096     // 2^12 amplitudes

typedef float f32x2 __attribute__((ext_vector_type(2)));

// CNOT ring: gates CNOT(i,(i+1)%12), wire j <-> bit (11-j).
// forward basis permutation pi(k), GF(2)-linear:
constexpr int ring_pi_c(int k) {
    int u = k ^ (k >> 1);
    u ^= u >> 2; u ^= u >> 4; u ^= u >> 8;
    int w0 = ((u >> 11) ^ u) & 1;
    return (u & 0x7FF) | (w0 << 11);
}
// inverse permutation sigma = pi^{-1}
constexpr int ring_sigma_c(int k) {
    int s = (k ^ (k >> 1)) & 0x3FF;
    int b10 = ((k >> 10) ^ (k >> 11) ^ k) & 1;
    int b11 = ((k >> 11) ^ k) & 1;
    return s | (b10 << 10) | (b11 << 11);
}
// storage swizzle (GF(2)-linear), proven benign conflicts (R7)
constexpr int sig2(int m) { return m ^ ((m >> 4) & 0xF) ^ ((m >> 8) & 0xF); }

// real Y-rotation (c,s): a0' = c*a0 - s*a1 ; a1' = s*a0 + c*a1  (4 pk insts)
__device__ __forceinline__ void ygate(f32x2 cs_, f32x2& a0, f32x2& a1) {
    f32x2 n0, n1;
    asm("v_pk_mul_f32 %0, %3, %4 op_sel:[0,1] op_sel_hi:[1,1] neg_lo:[0,1] neg_hi:[0,1]\n\t"
        "v_pk_fma_f32 %0, %2, %4, %0 op_sel:[0,0,0] op_sel_hi:[1,0,1]\n\t"
        "v_pk_mul_f32 %1, %2, %4 op_sel:[0,1] op_sel_hi:[1,1]\n\t"
        "v_pk_fma_f32 %1, %3, %4, %1 op_sel:[0,0,0] op_sel_hi:[1,0,1]"
        : "=&v"(n0), "=&v"(n1)
        : "v"(a0), "v"(a1), "v"(cs_));
    a0 = n0; a1 = n1;
}

// diagonal cmul: a = (p+iq)*(x+iy), e=(p,q)  (2 pk insts)
__device__ __forceinline__ void cdiag(f32x2 e, f32x2& a) {
    f32x2 m;
    asm("v_pk_mul_f32 %0, %1, %2 op_sel:[1,1] op_sel_hi:[0,1] neg_lo:[1,0]\n\t"
        "v_pk_fma_f32 %0, %1, %2, %0 op_sel:[0,0,0] op_sel_hi:[1,0,1]"
        : "=&v"(m) : "v"(a), "v"(e));
    a = m;
}

template<int P>
__device__ __forceinline__ void ygate_on_bit(f32x2 a[16], float2 cs_) {
    f32x2 v = f32x2{cs_.x, cs_.y};
    #pragma unroll
    for (int r = 0; r < 16; ++r)
        if (!(r & (1 << P)))
            ygate(v, a[r], a[r | (1 << P)]);
}

// ---- prep1: encode cos/sin + ZYZ decomposition of the 72 fused gates
__global__ void prep1_kernel(const float* __restrict__ x,     // (B,24)
                             const float* __restrict__ wts,   // (6,3,12)
                             float2* __restrict__ ys,         // 72 (cy,sy)
                             float2* __restrict__ cdah,       // 72 (c/2, d/2)
                             float2* __restrict__ cs,         // B*24
                             int total)
{
    int idx = blockIdx.x * blockDim.x + threadIdx.x;
    if (idx < total) {
        float th = 0.5f * x[idx];
        float s, c; sincosf(th, &s, &c);
        cs[idx] = make_float2(c, s);
    }
    if (idx < 72) {
        int ab = idx / 12, w = idx % 12;
        float a  = 0.5f * wts[(ab * 3 + 0) * 12 + w];
        float bb = 0.5f * wts[(ab * 3 + 1) * 12 + w];
        float g  = 0.5f * wts[(ab * 3 + 2) * 12 + w];
        float sa, ca, sb, cb, sg, cg;
        sincosf(a,  &sa, &ca);
        sincosf(bb, &sb, &cb);
        sincosf(g,  &sg, &cg);
        float A = cb * (ca * cg - sa * sg);   // U = Ry(g)Rz(2b)Ry(a) in ABCD form
        float B = sb * (ca * cg + sa * sg);
        float C = cb * (sa * cg + ca * sg);
        float D = sb * (sa * cg - ca * sg);
        // exact ZYZ: U = Rz(c)·Ry(t)·Rz(d); cy=cos(t/2)=|U00|, sy=sin(t/2)=|U10|
        float cy = sqrtf(A * A + B * B);
        float sy = sqrtf(C * C + D * D);
        float f00 = atan2f(-B, A);            // phase of U00 = A - iB
        float f10 = atan2f(D, C);             // phase of U10 = C + iD
        ys[idx]   = make_float2(cy, sy);
        cdah[idx] = make_float2(0.5f * (f10 - f00), -0.5f * (f10 + f00)); // (c/2, d/2)
    }
}

// ---- prep2: 7 diagonal tables E_l(k) (batch-independent)
// layers: 0,1,2 = ansatz 0..2; 3 = mid-RX; 4,5,6 = ansatz 3..5
// E_0=D0; E_l=D_l*C_{l-1}(sigma);  E_3=Kb*C_2(sigma); E_4=(D_3*Ka); Kb/Ka=Rz(+-pi/2)
__global__ void prep2_kernel(const float2* __restrict__ cdah,
                             float2* __restrict__ tabs)       // 7*4096
{
    int idx = blockIdx.x * blockDim.x + threadIdx.x;
    if (idx >= 7 * NS) return;
    int tl = idx >> 12, k = idx & (NS - 1);
    int sk = ring_sigma_c(k);
    const float QP = 0.7853981633974483f;   // pi/4
    float ph = 0.f;
    for (int w = 0; w < 12; ++w) {
        float zd = ((k  >> (11 - w)) & 1) ? 1.f : -1.f;
        float zc = ((sk >> (11 - w)) & 1) ? 1.f : -1.f;
        float dcf, ccf;
        if (tl == 3)      { dcf = QP;                       ccf = cdah[2 * 12 + w].x; }
        else if (tl == 4) { dcf = cdah[3 * 12 + w].y - QP;  ccf = 0.f; }
        else {
            int ald = (tl < 3) ? tl : tl - 1;
            dcf = cdah[ald * 12 + w].y;
            ccf = (tl == 0) ? 0.f : cdah[((tl < 3) ? tl - 1 : tl - 2) * 12 + w].x;
        }
        ph += zd * dcf + zc * ccf;
    }
    float s, c; sincosf(ph, &s, &c);
    tabs[idx] = make_float2(c, s);
}

__global__ __launch_bounds__(NT, 2)   // (256,2): proven no-spill regime; LDS 32KB -> 5 blocks/CU
void tqhea_kernel(const float2* __restrict__ ys,    // 72 (cy,sy)
                  const float2* __restrict__ cs,    // (B,24)
                  const f32x2*  __restrict__ tabs,  // 7*4096 diagonal tables
                  float* __restrict__ out)          // (B,1)
{
    __shared__ f32x2 psi[NS];        // 32 KB, sig2-swizzled storage

    const int b = blockIdx.x;
    const int t = threadIdx.x;

    const int lo = t & 0xF, h = t >> 4;
    const int tb     = (t & 0xF0) | (lo ^ h);          // P0: addr = (r<<8)|(tb^r)
    const int baseP1 = (h << 8) | (lo ^ h);            // P1: addr = baseP1 ^ 17r
    const int baseP2 = (t << 4) | (lo ^ h);            // P2: addr = baseP2 ^ r
    const int Qt     = sig2(ring_pi_c(t << 4));        // ring scatter: Qt ^ sig2(pi(r))
    const int Pt     = ring_pi_c(t << 4);              // reduction diag

    const float2* csb  = cs + b * 24;
    const float2* cs12 = csb + 12;

    // ---- init: |0..0> + first RX layer = product state (write-only pass)
    {
        float2 rc[12];
        #pragma unroll
        for (int i = 0; i < 12; ++i) rc[i] = csb[i];
        float mlo = 1.f;
        #pragma unroll
        for (int bit = 0; bit < 8; ++bit)
            mlo *= ((t >> bit) & 1) ? rc[11 - bit].y : rc[11 - bit].x;
        int pct = __popc(t);
        #pragma unroll
        for (int r = 0; r < 16; ++r) {
            float mhi = 1.f;
            #pragma unroll
            for (int p = 0; p < 4; ++p)
                mhi *= ((r >> p) & 1) ? rc[3 - p].y : rc[3 - p].x;
            float mag = mhi * mlo;
            int pc = (pct + __popc(r)) & 3;
            f32x2 v;
            v.x = (pc == 0) ? mag : ((pc == 2) ? -mag : 0.f);
            v.y = (pc == 1) ? -mag : ((pc == 3) ? mag : 0.f);
            psi[(r << 8) | (tb ^ r)] = v;
        }
    }
    __syncthreads();

    float acc = 0.f;

    // ---- 7 Y-layers (0..2 ansatz, 3 = mid-RX, 4..6 ansatz); diagonal table at P0;
    //      ring folded into P2 scatter (layers 0,1,2,4,5); layer 6 ring folds into <H>
    #pragma unroll 1
    for (int lay = 0; lay < 7; ++lay) {
        const bool isx = (lay == 3);
        const float2* yrow = isx ? cs12 : ys + ((lay < 3) ? lay : lay - 1) * 12;
        const f32x2* Tl = tabs + lay * NS;
        f32x2 a[16];

        // P0: wires 0..3 (k bits 11..8 reg-local); apply diagonal E_lay first
        f32x2 e[16];
        #pragma unroll
        for (int r = 0; r < 16; ++r) e[r] = Tl[(r << 8) | t];   // coalesced, L2
        #pragma unroll
        for (int r = 0; r < 16; ++r) a[r] = psi[(r << 8) | (tb ^ r)];
        #pragma unroll
        for (int r = 0; r < 16; ++r) cdiag(e[r], a[r]);
        ygate_on_bit<3>(a, yrow[0]);
        ygate_on_bit<2>(a, yrow[1]);
        ygate_on_bit<1>(a, yrow[2]);
        ygate_on_bit<0>(a, yrow[3]);
        #pragma unroll
        for (int r = 0; r < 16; ++r) psi[(r << 8) | (tb ^ r)] = a[r];
        __syncthreads();

        // P1: wires 4..7
        #pragma unroll
        for (int r = 0; r < 16; ++r) a[r] = psi[baseP1 ^ (17 * r)];
        ygate_on_bit<3>(a, yrow[4]);
        ygate_on_bit<2>(a, yrow[5]);
        ygate_on_bit<1>(a, yrow[6]);
        ygate_on_bit<0>(a, yrow[7]);
        #pragma unroll
        for (int r = 0; r < 16; ++r) psi[baseP1 ^ (17 * r)] = a[r];
        __syncthreads();

        // P2: wires 8..11; thread t, reg r hold k=(t<<4)|r
        #pragma unroll
        for (int r = 0; r < 16; ++r) a[r] = psi[baseP2 ^ r];
        if (lay < 6 && !isx) __syncthreads();   // WAR before ring scatter
        ygate_on_bit<3>(a, yrow[8]);
        ygate_on_bit<2>(a, yrow[9]);
        ygate_on_bit<1>(a, yrow[10]);
        ygate_on_bit<0>(a, yrow[11]);
        if (lay == 6) {
            // ---- <H>: final ring via pi; diag = 12 - 2*popc(pi(k))
            #pragma unroll
            for (int r = 0; r < 16; ++r) {
                float d = 12.0f - 2.0f * (float)__popc(Pt ^ ring_pi_c(r));
                acc += (a[r].x * a[r].x + a[r].y * a[r].y) * d;
            }
        } else if (isx) {
            #pragma unroll
            for (int r = 0; r < 16; ++r) psi[baseP2 ^ r] = a[r];   // in-place, no ring
            __syncthreads();
        } else {
            #pragma unroll
            for (int r = 0; r < 16; ++r) psi[Qt ^ sig2(ring_pi_c(r))] = a[r];
            __syncthreads();
        }
    }

    // ---- reduce: wave shfl, then cross-wave via psi reuse
    #pragma unroll
    for (int off = 32; off > 0; off >>= 1)
        acc += __shfl_down(acc, off);
    __syncthreads();
    if ((t & 63) == 0) ((float*)psi)[t >> 6] = acc;
    __syncthreads();
    if (t == 0) {
        const float* rb = (const float*)psi;
        out[b] = rb[0] + rb[1] + rb[2] + rb[3];
    }
}

extern "C" void kernel_launch(void* const* d_in, const int* in_sizes, int n_in,
                              void* d_out, int out_size, void* d_ws, size_t ws_size,
                              hipStream_t stream) {
    const float* x   = (const float*)d_in[0];   // (B, 24) float32
    const float* wts = (const float*)d_in[1];   // (6, 3, 12) float32
    float* out = (float*)d_out;                 // (B, 1) float32
    int B = in_sizes[0] / 24;
    int total = B * 24;

    char* ws = (char*)d_ws;
    float2* ys   = (float2*)(ws);                         // 576 B
    float2* cdah = (float2*)(ws + 576);                   // 576 B
    float2* cs   = (float2*)(ws + 1152);                  // B*24*8
    float2* tabs = (float2*)(ws + 1152 + (size_t)total * 8);  // 7*4096*8

    prep1_kernel<<<dim3((total + NTP - 1) / NTP), dim3(NTP), 0, stream>>>(x, wts, ys, cdah, cs, total);
    prep2_kernel<<<dim3((7 * NS + NTP - 1) / NTP), dim3(NTP), 0, stream>>>(cdah, tabs);
    tqhea_kernel<<<dim3(B), dim3(NT), 0, stream>>>(ys, cs, (const f32x2*)tabs, out);
}